// Round 8
// baseline (115.160 us; speedup 1.0000x reference)
//
#include <hip/hip_runtime.h>

// Problem constants (match reference)
constexpr int V     = 50265;   // vocab size
constexpr int PADT  = 1;       // PAD token id
constexpr int BATCH = 512;
constexpr int SEQ   = 512;
constexpr int SS    = 6284;    // vocab section (8 sections cover V)
constexpr int HW4   = 3144;    // 3142 packed u16-pair words, padded to uint4
constexpr int GRID  = BATCH * 4;  // 2048 = 8 blocks/CU * 256 CUs (co-resident)

// Tiny init: zero the two global counters (d_ws is 0xAA-poisoned; counters
// must start at 0 every call -- deterministic, no cross-call state).
__global__ void k_init(int* __restrict__ cnt) { cnt[0] = 0; cnt[1] = 0; }

// Single fused kernel. Grid 2048 x 256 = exactly full residency
// (__launch_bounds__(256,8) caps VGPR<=64; 12.6KB LDS * 8 = 101KB < 160KB),
// so a device-scope spin barrier is deadlock-free. Each row's h==0 block
// publishes the row's non-PAD length; every block overlaps the wait with its
// histogram zero + scatter, then streams its two vocab sections: output
// written exactly once, coalesced scalar stores (R7: float4 was null;
// R4: nontemporal regressed 2x).
__global__ __launch_bounds__(256, 8) void k_fused(const int* __restrict__ ids,
                                                  int* __restrict__ cnt,
                                                  float* __restrict__ out) {
    __shared__ unsigned hist[HW4];
    __shared__ int s_red[4];
    __shared__ float s_add;

    const int bs = blockIdx.x;
    const int b = bs >> 2, h = bs & 3;   // row, quarter
    const int t = threadIdx.x;

    const int id0 = ids[b * SEQ + t];
    const int id1 = ids[b * SEQ + 256 + t];

    // row non-PAD length (block reduce over 4 waves)
    int np = ((id0 != PADT) ? 1 : 0) + ((id1 != PADT) ? 1 : 0);
    #pragma unroll
    for (int off = 32; off > 0; off >>= 1) np += __shfl_down(np, off, 64);
    if ((t & 63) == 0) s_red[t >> 6] = np;
    __syncthreads();

    // one block per row publishes dl; release on cnt[1] orders the cnt[0] add
    if (h == 0 && t == 0) {
        const int dl = s_red[0] + s_red[1] + s_red[2] + s_red[3];
        __hip_atomic_fetch_add(&cnt[0], dl, __ATOMIC_RELAXED, __HIP_MEMORY_SCOPE_AGENT);
        __hip_atomic_fetch_add(&cnt[1], 1,  __ATOMIC_RELEASE, __HIP_MEMORY_SCOPE_AGENT);
    }

    const int sh = (t & 1) * 16;          // loop-invariant unpack shift
    float* __restrict__ orow = out + (size_t)b * V;

    #pragma unroll 1
    for (int ph = 0; ph < 2; ++ph) {
        const int q = h * 2 + ph;
        const int v0 = q * SS;
        const int vend = (v0 + SS < V) ? (v0 + SS) : V;

        // zero histogram with 16B LDS writes (overlaps the global reduce)
        uint4* h4 = (uint4*)hist;
        const uint4 z4 = make_uint4(0u, 0u, 0u, 0u);
        #pragma unroll
        for (int w = t; w < HW4 / 4; w += 256) h4[w] = z4;
        __syncthreads();

        // scatter my 2 tokens if in this section (u16-packed; counts <= 512)
        if (id0 != PADT && id0 >= v0 && id0 < vend) {
            const int li = id0 - v0;
            atomicAdd(&hist[li >> 1], 1u << ((li & 1) * 16));
        }
        if (id1 != PADT && id1 >= v0 && id1 < vend) {
            const int li = id1 - v0;
            atomicAdd(&hist[li >> 1], 1u << ((li & 1) * 16));
        }

        if (ph == 0) {
            // wait for all 512 row-publishes, then compute addend locally.
            // All 2048 blocks are co-resident -> no deadlock.
            if (t == 0) {
                while (__hip_atomic_load(&cnt[1], __ATOMIC_ACQUIRE,
                                         __HIP_MEMORY_SCOPE_AGENT) < BATCH)
                    __builtin_amdgcn_s_sleep(2);
                const int total = __hip_atomic_load(&cnt[0], __ATOMIC_RELAXED,
                                                    __HIP_MEMORY_SCOPE_AGENT);
                const int dl = s_red[0] + s_red[1] + s_red[2] + s_red[3];
                // d_avg = dl / (total/BATCH); dl*BATCH <= 2^18, exact in fp32
                const float d_avg = (float)dl * (float)BATCH / (float)total;
                s_add = 1.6f * (0.25f + 0.75f * d_avg);  // k*(1-b+b*d_avg)
            }
        }
        __syncthreads();

        const float addend = s_add;
        // stream the section: lane-consecutive words (2-way broadcast LDS
        // reads, conflict-free), 256B/wave dense stores.
        // fc==0 -> (0*2.6)*rcp(addend) == 0 exactly; rcp err ~1ulp << 3.4e-2.
        for (int v = v0 + t; v < vend; v += 256) {
            const unsigned cw = hist[(v - v0) >> 1];
            const float fc = (float)((cw >> sh) & 0xffffu);
            orow[v] = (fc * 2.6f) * __builtin_amdgcn_rcpf(fc + addend);
        }
        __syncthreads();   // protect hist re-zero of the next section
    }
}

extern "C" void kernel_launch(void* const* d_in, const int* in_sizes, int n_in,
                              void* d_out, int out_size, void* d_ws, size_t ws_size,
                              hipStream_t stream) {
    const int* ids = (const int*)d_in[0];   // input_ids, int32 [512*512]
    // d_in[1] = beta (unused by the reference computation)
    float* out = (float*)d_out;             // [512 * 50265] fp32
    int* cnt = (int*)d_ws;                  // cnt[0]=total, cnt[1]=done

    k_init<<<1, 1, 0, stream>>>(cnt);
    k_fused<<<GRID, 256, 0, stream>>>(ids, cnt, out);
}

// Round 9
// 26.721 us; speedup vs baseline: 4.3098x; 4.3098x over previous
//
#include <hip/hip_runtime.h>

// Problem constants (match reference)
constexpr int V     = 50265;   // vocab size
constexpr int PADT  = 1;       // PAD token id
constexpr int BATCH = 512;
constexpr int SEQ   = 512;
constexpr int HS    = 25134;   // vocab half (even; 2*HS >= V)
constexpr int HW    = HS / 2;  // 12567 packed u16-pair words
constexpr int HW4   = 12568;   // padded to uint4 multiple (49.1 KB)
constexpr int NPART = 64;      // one wave's worth of partials

// Kernel 1: 64 block-partials of the global non-PAD token count.
// Every slot written every call (no zero-init dependency, deterministic).
__global__ __launch_bounds__(512) void k_partial(const int4* __restrict__ ids4,
                                                 int* __restrict__ partials) {
    const int t = threadIdx.x, b = blockIdx.x;
    const int4 a = ids4[b * 1024 + t];          // 64 blk * 512 thr * 8 tok = 262144
    const int4 c4 = ids4[b * 1024 + 512 + t];
    int c = (a.x != PADT) + (a.y != PADT) + (a.z != PADT) + (a.w != PADT)
          + (c4.x != PADT) + (c4.y != PADT) + (c4.z != PADT) + (c4.w != PADT);
    #pragma unroll
    for (int off = 32; off > 0; off >>= 1) c += __shfl_down(c, off, 64);
    __shared__ int sc[8];
    if ((t & 63) == 0) sc[t >> 6] = c;
    __syncthreads();
    if (t == 0) {
        int s = 0;
        #pragma unroll
        for (int j = 0; j < 8; ++j) s += sc[j];
        partials[b] = s;
    }
}

// Kernel 2: 512 blocks x 512 threads, one block = (row, vocab-half).
// 49.1 KB u16-packed LDS hist -> 2 blocks/CU, ONE fully-resident round,
// and only 512 concurrent HBM write streams (was 2048) to restore DRAM
// row locality. Output written exactly once, coalesced scalar stores
// (R7: float4 null; R4: nontemporal -2x; R8: device-scope spin -5x).
__global__ __launch_bounds__(512) void k_fused(const int* __restrict__ ids,
                                               const int* __restrict__ partials,
                                               float* __restrict__ out) {
    __shared__ unsigned hist[HW4];
    __shared__ int s_red[8];
    __shared__ float s_add;

    const int bs = blockIdx.x;
    const int b = bs >> 1, h = bs & 1;   // row, half
    const int t = threadIdx.x;
    const int v0 = h * HS;
    const int vend = (v0 + HS < V) ? (v0 + HS) : V;

    // issue global loads immediately; latency hides under hist zeroing
    int pv = (t < NPART) ? partials[t] : 0;
    const int id = ids[b * SEQ + t];

    // zero histogram with 16B LDS writes (3142 uint4 / 512 thr ~ 6 iters)
    uint4* h4 = (uint4*)hist;
    const uint4 z4 = make_uint4(0u, 0u, 0u, 0u);
    #pragma unroll
    for (int w = t; w < HW4 / 4; w += 512) h4[w] = z4;
    __syncthreads();

    // scatter my token if it lands in this half (u16-packed; counts <= 512)
    if (id != PADT && id >= v0 && id < vend) {
        const int li = id - v0;
        atomicAdd(&hist[li >> 1], 1u << ((li & 1) * 16));
    }

    // row non-PAD length (block reduce over 8 waves)
    int np = (id != PADT) ? 1 : 0;
    #pragma unroll
    for (int off = 32; off > 0; off >>= 1) np += __shfl_down(np, off, 64);
    if ((t & 63) == 0) s_red[t >> 6] = np;
    __syncthreads();

    if (t < NPART) {
        // wave-parallel global total (loads issued at kernel entry)
        #pragma unroll
        for (int off = 32; off > 0; off >>= 1) pv += __shfl_down(pv, off, 64);
        if (t == 0) {
            int dl = 0;
            #pragma unroll
            for (int j = 0; j < 8; ++j) dl += s_red[j];
            // d_avg = dl / (total/BATCH); dl*BATCH <= 2^18, exact in fp32
            float d_avg = (float)dl * (float)BATCH / (float)pv;
            s_add = 1.6f * (0.25f + 0.75f * d_avg);  // k*(1-b+b*d_avg)
        }
    }
    __syncthreads();

    const float addend = s_add;
    const int sh = (t & 1) * 16;          // loop-invariant unpack shift
    float* __restrict__ orow = out + (size_t)b * V;

    // stream this half: lane-consecutive words (2-way broadcast LDS reads,
    // conflict-free), 256B/wave dense stores.
    // fc==0 -> (0*2.6)*rcp(addend) == 0 exactly; rcp err ~1ulp << 3.4e-2.
    for (int v = v0 + t; v < vend; v += 512) {
        const unsigned cw = hist[(v - v0) >> 1];
        const float fc = (float)((cw >> sh) & 0xffffu);
        orow[v] = (fc * 2.6f) * __builtin_amdgcn_rcpf(fc + addend);
    }
}

extern "C" void kernel_launch(void* const* d_in, const int* in_sizes, int n_in,
                              void* d_out, int out_size, void* d_ws, size_t ws_size,
                              hipStream_t stream) {
    const int* ids = (const int*)d_in[0];   // input_ids, int32 [512*512]
    // d_in[1] = beta (unused by the reference computation)
    float* out = (float*)d_out;             // [512 * 50265] fp32
    int* partials = (int*)d_ws;             // NPART ints of scratch

    k_partial<<<NPART, 512, 0, stream>>>((const int4*)ids, partials);
    k_fused<<<BATCH * 2, 512, 0, stream>>>(ids, partials, out);
}